// Round 7
// baseline (4942.447 us; speedup 1.0000x reference)
//
#include <hip/hip_runtime.h>

#define SEQ   512
#define BATCH 128
#define NFEAT 64
#define HID   256
#define HB    (BATCH * HID)   // 32768
#define NGRP  8               // batch groups (16 batches each)

// ---------------------------------------------------------------------------
// Persistent 2-layer LSTM, 256 blocks x 256 threads (1 block/CU).
// Group g: 32 blocks = 2 layers x 16 col-tiles, owns batches [g*16,g*16+16).
// Each layer free-runs its own t; cross-block h exchange uses TAGGED WORDS:
//   u64 = [tag=t+1 : 32 | bf16_hi : 16 | bf16_lo : 16]   (one word per h value)
// Producers: ONE relaxed agent u64 store per thread per step (no flags, no
// drain). Consumers: poll the needed words until tag matches -> single IF
// round trip, payload pre-split into bf16 hi/lo (no consumer conversion).
// Back-pressure: within a layer the all-to-all tag chain bounds skew to 1
// (observing peers' step-t words proves they consumed my t-1 words), making
// the parity double-buffer safe. Layer-1's one-directional read of h0 is
// guarded by a lazy progress flag (l1prog) that layer-0 checks before
// overwriting (>= t-2; never hot in steady state).
// Matmul: round-6-verified MFMA bf16 hi/lo split path (A-frags resident in
// VGPRs, swizzled LDS B-planes). red buffer relaid to [w][g][batch][20] with
// float4 stores (bank-conflict floor). c state stays in a register.
// ---------------------------------------------------------------------------

typedef unsigned long long u64;
typedef __attribute__((ext_vector_type(8))) short  short8;
typedef __attribute__((ext_vector_type(4))) float  f32x4;
typedef __attribute__((ext_vector_type(4))) unsigned short us4;

__device__ __forceinline__ unsigned short f2bf(float f) {  // RNE
    union { float f; unsigned u; } c; c.f = f;
    unsigned r = c.u + 0x7FFF + ((c.u >> 16) & 1);
    return (unsigned short)(r >> 16);
}
__device__ __forceinline__ float bf2f(unsigned short h) {
    union { float f; unsigned u; } c; c.u = ((unsigned)h) << 16;
    return c.f;
}

__device__ __forceinline__ u64 ald64(const u64* p) {
    return __hip_atomic_load(p, __ATOMIC_RELAXED, __HIP_MEMORY_SCOPE_AGENT);
}
__device__ __forceinline__ void ast64(u64* p, u64 v) {
    __hip_atomic_store(p, v, __ATOMIC_RELAXED, __HIP_MEMORY_SCOPE_AGENT);
}
__device__ __forceinline__ unsigned ald32(const unsigned* p) {
    return __hip_atomic_load(p, __ATOMIC_RELAXED, __HIP_MEMORY_SCOPE_AGENT);
}
__device__ __forceinline__ void ast32(unsigned* p, unsigned v) {
    __hip_atomic_store(p, v, __ATOMIC_RELAXED, __HIP_MEMORY_SCOPE_AGENT);
}

__global__ __launch_bounds__(256, 1) void lstm_persist(
    const float* __restrict__ X,      // [512][128][64]
    const float* __restrict__ w_ih0,  // [1024][64]
    const float* __restrict__ w_hh0,  // [1024][256]
    const float* __restrict__ b_ih0,
    const float* __restrict__ b_hh0,
    const float* __restrict__ w_ih1,  // [1024][256]
    const float* __restrict__ w_hh1,  // [1024][256]
    const float* __restrict__ b_ih1,
    const float* __restrict__ b_hh1,
    u64* __restrict__ h0w,            // [2][BATCH][HID] tagged words
    u64* __restrict__ h1w,            // [2][BATCH][HID] tagged words
    unsigned* __restrict__ l1prog)    // [NGRP][16] stride 32 u32
{
    const int bid = blockIdx.x;
    const int tid = threadIdx.x;
    const int g     = bid >> 5;        // batch group 0..7
    const int r     = bid & 31;        // rank in group
    const int layer = r >> 4;          // 0 or 1
    const int ct    = r & 15;          // col tile
    const int b0    = g * 16;          // 16 batches
    const int j0    = ct * 16;         // 16 h-cols

    const int wave = tid >> 6;
    const int l    = tid & 63;
    const int kq   = l >> 4;           // k-quarter within a k-tile
    const int ar   = l & 15;           // A row / B col (batch) within tile

    // bf16 planes of the [x;h] concat (k = 512; layer0 uses [0,320), rest 0)
    __shared__ __align__(16) unsigned short hsh[16 * 512];
    __shared__ __align__(16) unsigned short hsl[16 * 512];
    __shared__ float red[4][4][16][20];   // [wave][gate][batch(ar)][col], f4 stores
    __shared__ float bbuf[4][16];         // bias sums [gate][col]

    // zero bf16 planes once (layer0's k >= 320 must stay 0 forever)
    {
        const short8 z8 = {0, 0, 0, 0, 0, 0, 0, 0};
        for (int i = tid; i < 16 * 512 / 8; i += 256) {
            ((short8*)hsh)[i] = z8;
            ((short8*)hsl)[i] = z8;
        }
    }
    if (tid < 64) {
        const int gg = tid >> 4, cc = tid & 15;
        const float* bi_ = layer ? b_ih1 : b_ih0;
        const float* bh_ = layer ? b_hh1 : b_hh0;
        bbuf[gg][cc] = bi_[gg * 256 + j0 + cc] + bh_[gg * 256 + j0 + cc];
    }

    // ---- A-fragments: weight slice -> bf16 hi/lo, resident in VGPRs ----
    // (verbatim round-6-verified layout)
    short8 Ahi[4][4], Alo[4][4];  // [gate(Mtile)][wave-local ktile]
    {
        const short8 z8 = {0, 0, 0, 0, 0, 0, 0, 0};
        #pragma unroll
        for (int gg = 0; gg < 4; ++gg) {
            const int row = gg * 256 + j0 + ar;
            #pragma unroll
            for (int kt = 0; kt < 4; ++kt) {
                const int k = (wave * 4 + kt) * 32 + kq * 8;  // concat-k of 8 floats
                const float* src = nullptr;
                if (layer) {
                    src = (k < 256) ? (w_ih1 + (size_t)row * 256 + k)
                                    : (w_hh1 + (size_t)row * 256 + (k - 256));
                } else {
                    if (k < 64)       src = w_ih0 + (size_t)row * 64 + k;
                    else if (k < 320) src = w_hh0 + (size_t)row * 256 + (k - 64);
                }
                short8 hi8 = z8, lo8 = z8;
                if (src) {
                    const float4 a = ((const float4*)src)[0];
                    const float4 b = ((const float4*)src)[1];
                    const float wv[8] = {a.x, a.y, a.z, a.w, b.x, b.y, b.z, b.w};
                    #pragma unroll
                    for (int i = 0; i < 8; ++i) {
                        const unsigned short h = f2bf(wv[i]);
                        hi8[i] = (short)h;
                        lo8[i] = (short)f2bf(wv[i] - bf2f(h));
                    }
                }
                Ahi[gg][kt] = hi8;
                Alo[gg][kt] = lo8;
            }
        }
    }

    // elementwise ownership: thread (eb=batch, ecc=col); c stays in a register
    const int eb = tid >> 4, ecc = tid & 15;
    float creg = 0.f;

    u64*      hown = layer ? h1w : h0w;
    unsigned* prog = l1prog + (size_t)g * 16 * 32;
    const int hoff = layer ? 256 : 64;   // k-offset of the h_prev region

    // X prefetch (layer 0): one float4/thread covers 16 batches x 64 floats
    const int pb = tid >> 4, pf = tid & 15;
    float4 xpf = make_float4(0.f, 0.f, 0.f, 0.f);
    if (!layer)
        xpf = ((const float4*)(X + (size_t)(b0 + pb) * NFEAT))[pf];

    __syncthreads();  // LDS zero + bias visible

    for (int t = 0; t < SEQ; ++t) {
        const int par = t & 1, pp = par ^ 1;
        const int b = tid >> 4, f0 = tid & 15;   // staging: batch row, col-chunk
        const int swz = (b & 7) << 3;

        // ---- staging: poll tagged words, unpack straight into LDS planes ----
        if (t > 0) {  // h_prev (own layer), words tagged t, parity pp
            const u64* src = hown + ((size_t)pp * BATCH + b0 + b) * HID + f0 * 16;
            u64 v[16];
            const unsigned wtag = (unsigned)t;
            int guard = 0; bool ok;
            do {
                ok = true;
                #pragma unroll
                for (int i = 0; i < 16; ++i) v[i] = ald64(src + i);
                #pragma unroll
                for (int i = 0; i < 16; ++i) ok &= ((unsigned)(v[i] >> 32) == wtag);
            } while (!ok && ++guard < (1 << 16));
            short8 h0v, h1v, l0v, l1v;
            #pragma unroll
            for (int i = 0; i < 8; ++i) {
                h0v[i] = (short)((v[i] >> 16) & 0xffff);
                l0v[i] = (short)(v[i] & 0xffff);
                h1v[i] = (short)((v[i + 8] >> 16) & 0xffff);
                l1v[i] = (short)(v[i + 8] & 0xffff);
            }
            const int us = b * 512 + hoff + f0 * 16;
            *(short8*)&hsh[us ^ swz]       = h0v;
            *(short8*)&hsh[(us + 8) ^ swz] = h1v;
            *(short8*)&hsl[us ^ swz]       = l0v;
            *(short8*)&hsl[(us + 8) ^ swz] = l1v;
        }
        if (layer) {  // x = h0[t], words tagged t+1, parity par
            const u64* src = h0w + ((size_t)par * BATCH + b0 + b) * HID + f0 * 16;
            u64 v[16];
            const unsigned wtag = (unsigned)(t + 1);
            int guard = 0; bool ok;
            do {
                ok = true;
                #pragma unroll
                for (int i = 0; i < 16; ++i) v[i] = ald64(src + i);
                #pragma unroll
                for (int i = 0; i < 16; ++i) ok &= ((unsigned)(v[i] >> 32) == wtag);
            } while (!ok && ++guard < (1 << 16));
            short8 h0v, h1v, l0v, l1v;
            #pragma unroll
            for (int i = 0; i < 8; ++i) {
                h0v[i] = (short)((v[i] >> 16) & 0xffff);
                l0v[i] = (short)(v[i] & 0xffff);
                h1v[i] = (short)((v[i + 8] >> 16) & 0xffff);
                l1v[i] = (short)(v[i + 8] & 0xffff);
            }
            const int us = b * 512 + f0 * 16;
            *(short8*)&hsh[us ^ swz]       = h0v;
            *(short8*)&hsh[(us + 8) ^ swz] = h1v;
            *(short8*)&hsl[us ^ swz]       = l0v;
            *(short8*)&hsl[(us + 8) ^ swz] = l1v;
        } else {      // x from prefetched X
            const float xv[4] = {xpf.x, xpf.y, xpf.z, xpf.w};
            us4 xh, xl;
            #pragma unroll
            for (int i = 0; i < 4; ++i) {
                const unsigned short hh = f2bf(xv[i]);
                xh[i] = hh;
                xl[i] = f2bf(xv[i] - bf2f(hh));
            }
            const int us = pb * 512 + pf * 4;
            const int sw = (pb & 7) << 3;
            *(us4*)&hsh[us ^ sw] = xh;
            *(us4*)&hsl[us ^ sw] = xl;
        }
        __syncthreads();  // S1: staged planes visible

        // progress post (layer 1) / next X prefetch (layer 0)
        if (layer) {
            if (tid == 0) ast32(&prog[ct * 32], (unsigned)(t + 1));
        } else if (t + 1 < SEQ) {
            xpf = ((const float4*)(X + (size_t)(t + 1) * BATCH * NFEAT
                                     + (size_t)(b0 + pb) * NFEAT))[pf];
        }

        // ---- MFMA compute (round-6-verified addressing) ----
        {
            f32x4 acc[4];
            #pragma unroll
            for (int gg = 0; gg < 4; ++gg)
                acc[gg] = (f32x4){0.f, 0.f, 0.f, 0.f};

            #pragma unroll
            for (int kt = 0; kt < 4; ++kt) {
                const int KT = wave * 4 + kt;
                const int us = ar * 512 + KT * 32 + kq * 8;
                const int uswz = us ^ ((ar & 7) << 3);
                const short8 bh = *(const short8*)&hsh[uswz];
                const short8 bl = *(const short8*)&hsl[uswz];
                #pragma unroll
                for (int gg = 0; gg < 4; ++gg)
                    acc[gg] = __builtin_amdgcn_mfma_f32_16x16x32_bf16(
                        Ahi[gg][kt], bh, acc[gg], 0, 0, 0);
                #pragma unroll
                for (int gg = 0; gg < 4; ++gg)
                    acc[gg] = __builtin_amdgcn_mfma_f32_16x16x32_bf16(
                        Alo[gg][kt], bh, acc[gg], 0, 0, 0);
                #pragma unroll
                for (int gg = 0; gg < 4; ++gg)
                    acc[gg] = __builtin_amdgcn_mfma_f32_16x16x32_bf16(
                        Ahi[gg][kt], bl, acc[gg], 0, 0, 0);
            }
            // partial C -> LDS, float4, conflict-floor layout
            // C layout: col(batch)=lane&15=ar, row(colidx)=(lane>>4)*4+i=kq*4+i
            #pragma unroll
            for (int gg = 0; gg < 4; ++gg)
                *(f32x4*)&red[wave][gg][ar][kq * 4] = acc[gg];
        }
        __syncthreads();  // S2: partials visible

        // ---- cross-wave reduce + gates + state update ----
        float hv;
        {
            float p[4];
            #pragma unroll
            for (int gg = 0; gg < 4; ++gg)
                p[gg] = bbuf[gg][ecc] + red[0][gg][eb][ecc] + red[1][gg][eb][ecc]
                                      + red[2][gg][eb][ecc] + red[3][gg][eb][ecc];
            const float ig  = 1.0f / (1.0f + __expf(-p[0]));
            const float fg  = 1.0f / (1.0f + __expf(-p[1]));
            const float gg_ = tanhf(p[2]);
            const float og  = 1.0f / (1.0f + __expf(-p[3]));
            creg = fg * creg + ig * gg_;
            hv   = og * tanhf(creg);
        }

        // back-pressure: layer 0 must not overwrite h0[t-2] words before all
        // 16 layer-1 blocks staged step t-2 (posted value >= t-1). Lazy.
        if (!layer && t >= 2 && tid < 16) {
            int guard = 0;
            while (ald32(&prog[tid * 32]) < (unsigned)(t - 1) &&
                   ++guard < (1 << 16)) { }
        }
        __syncthreads();  // S3: red reads done, back-pressure cleared

        // ---- publish tagged word (single store; no flags, no drain) ----
        {
            const unsigned short hi = f2bf(hv);
            const unsigned short lo = f2bf(hv - bf2f(hi));
            const u64 wv = ((u64)(unsigned)(t + 1) << 32)
                         | ((unsigned)hi << 16) | (unsigned)lo;
            ast64(&hown[((size_t)par * BATCH + b0 + eb) * HID + j0 + ecc], wv);
        }
    }
}

// out[b] = dot(h1_last[b,:], fc_w) + fc_b ; h1 arrives as tagged hi/lo words
__global__ __launch_bounds__(64) void fc_kernel(
    const u64* __restrict__ h1last_w,
    const float* __restrict__ fc_w,
    const float* __restrict__ fc_b,
    float* __restrict__ out)
{
    const int b    = blockIdx.x;
    const int lane = threadIdx.x;
    float sum = 0.0f;
    #pragma unroll
    for (int k = lane; k < HID; k += 64) {
        const u64 w = h1last_w[(size_t)b * HID + k];
        const float h = bf2f((unsigned short)((w >> 16) & 0xffff))
                      + bf2f((unsigned short)(w & 0xffff));
        sum += h * fc_w[k];
    }
    #pragma unroll
    for (int off = 32; off > 0; off >>= 1)
        sum += __shfl_down(sum, off);
    if (lane == 0) out[b] = sum + fc_b[0];
}

extern "C" void kernel_launch(void* const* d_in, const int* in_sizes, int n_in,
                              void* d_out, int out_size, void* d_ws, size_t ws_size,
                              hipStream_t stream)
{
    const float* X     = (const float*)d_in[0];
    const float* w_ih0 = (const float*)d_in[1];
    const float* w_hh0 = (const float*)d_in[2];
    const float* b_ih0 = (const float*)d_in[3];
    const float* b_hh0 = (const float*)d_in[4];
    const float* w_ih1 = (const float*)d_in[5];
    const float* w_hh1 = (const float*)d_in[6];
    const float* b_ih1 = (const float*)d_in[7];
    const float* b_hh1 = (const float*)d_in[8];
    const float* fc_w  = (const float*)d_in[9];
    const float* fc_b  = (const float*)d_in[10];

    u64*      h0w    = (u64*)d_ws;            // [2][BATCH][HID] tagged
    u64*      h1w    = h0w + 2 * HB;          // [2][BATCH][HID] tagged
    unsigned* l1prog = (unsigned*)(h1w + 2 * HB);  // [NGRP][16] stride 32

    // zero tags + progress every call (the captured graph replays this memset,
    // so stale tags from a previous replay can never satisfy a poll)
    const size_t zbytes = (size_t)4 * HB * sizeof(u64) + NGRP * 16 * 32 * 4;
    (void)hipMemsetAsync(d_ws, 0, zbytes, stream);

    lstm_persist<<<NGRP * 32, 256, 0, stream>>>(X,
        w_ih0, w_hh0, b_ih0, b_hh0,
        w_ih1, w_hh1, b_ih1, b_hh1,
        h0w, h1w, l1prog);

    // h1 for t=511 lives in parity buffer (511 & 1) = 1
    fc_kernel<<<BATCH, 64, 0, stream>>>(h1w + HB, fc_w, fc_b, (float*)d_out);
}

// Round 9
// 2115.286 us; speedup vs baseline: 2.3365x; 2.3365x over previous
//
#include <hip/hip_runtime.h>

#define SEQ   512
#define BATCH 128
#define NFEAT 64
#define HID   256
#define HB    (BATCH * HID)   // 32768
#define NGRP  8               // batch groups (16 batches each)
#define GBLK  32              // blocks per group: 2 layers x 16 col-tiles

// ---------------------------------------------------------------------------
// Persistent 2-layer LSTM, 256 blocks x 256 threads (1 block/CU).
// Group g (32 blocks = 2 layers x 16 col-tiles) owns batches [g*16,g*16+16),
// pipelined: layer 0 at t=s, layer 1 at t=s-1. Cross-block h exchange uses
// ONLY the round-6-verified primitives: agent-scope RELAXED atomics (sc0 sc1,
// coherent at the Infinity Fabric) for h words and barrier flags. h crosses
// blocks as packed u32 [bf16_hi | bf16_lo] (round-7-verified, absmax 0.0):
// producer packs its single value; consumers unpack with shifts only.
// Flag barrier (round-6-verified): after __syncthreads() drains vmcnt (h
// stores acked at the coherence point), rank rk posts round s+1 to its flag;
// 32 lanes poll the 32 flags with s_sleep backoff.
// Ordering note: the unified 32-block barrier also orders layer-1's reads of
// h0[s-2] (complete before its flag post at s-1) before layer-0's overwrite
// at step s (starts only after barrier s-1 releases) -- no extra flag needed.
// Matmul: round-6-verified MFMA bf16 hi/lo split (A-frags resident in VGPRs,
// XOR-swizzled LDS B-planes, 48 MFMA/wave/step); partial C stored as float4
// into red[4][4][16][20] (conflict floor). c state stays in a register.
// ---------------------------------------------------------------------------

typedef unsigned u32;
typedef unsigned long long u64;
typedef __attribute__((ext_vector_type(8))) short  short8;
typedef __attribute__((ext_vector_type(4))) float  f32x4;
typedef __attribute__((ext_vector_type(4))) unsigned short us4;

__device__ __forceinline__ unsigned short f2bf(float f) {  // RNE
    union { float f; unsigned u; } c; c.f = f;
    unsigned r = c.u + 0x7FFF + ((c.u >> 16) & 1);
    return (unsigned short)(r >> 16);
}
__device__ __forceinline__ float bf2f(unsigned short h) {
    union { float f; unsigned u; } c; c.u = ((unsigned)h) << 16;
    return c.f;
}

// agent-scope (IF coherence point) relaxed atomics -- the ONLY cross-block
// memory primitives in this kernel (round-6-verified codegen).
__device__ __forceinline__ u64 ald64(const u64* p) {
    return __hip_atomic_load(p, __ATOMIC_RELAXED, __HIP_MEMORY_SCOPE_AGENT);
}
__device__ __forceinline__ u32 ald32(const u32* p) {
    return __hip_atomic_load(p, __ATOMIC_RELAXED, __HIP_MEMORY_SCOPE_AGENT);
}
__device__ __forceinline__ void ast32(u32* p, u32 v) {
    __hip_atomic_store(p, v, __ATOMIC_RELAXED, __HIP_MEMORY_SCOPE_AGENT);
}

__global__ __launch_bounds__(256, 1) void lstm_persist(
    const float* __restrict__ X,      // [512][128][64]
    const float* __restrict__ w_ih0,  // [1024][64]
    const float* __restrict__ w_hh0,  // [1024][256]
    const float* __restrict__ b_ih0,
    const float* __restrict__ b_hh0,
    const float* __restrict__ w_ih1,  // [1024][256]
    const float* __restrict__ w_hh1,  // [1024][256]
    const float* __restrict__ b_ih1,
    const float* __restrict__ b_hh1,
    u32* __restrict__ h0p,            // [2][HB] packed hi|lo
    u32* __restrict__ h1p,            // [2][HB] packed hi|lo
    u32* __restrict__ flags)          // [NGRP][GBLK] stride 32 u32 (128 B)
{
    const int bid = blockIdx.x;
    const int tid = threadIdx.x;
    const int g     = bid >> 5;        // batch group 0..7
    const int rk    = bid & 31;        // rank in group
    const int layer = rk >> 4;         // 0 or 1
    const int ct    = rk & 15;         // col tile
    const int b0    = g * 16;          // 16 batches
    const int j0    = ct * 16;         // 16 h-cols

    const int wave = tid >> 6;
    const int l    = tid & 63;
    const int kq   = l >> 4;           // k-quarter within a k-tile
    const int ar   = l & 15;           // A row / B col (batch) within tile

    // bf16 planes of the [x;h] concat (k = 512; layer0 uses [0,320), rest 0)
    __shared__ __align__(16) unsigned short hsh[16 * 512];
    __shared__ __align__(16) unsigned short hsl[16 * 512];
    __shared__ float red[4][4][16][20];   // [wave][gate][batch(ar)][col], f4 st
    __shared__ float bbuf[4][16];         // bias sums [gate][col]

    // zero bf16 planes once (layer0's k >= 320 must stay 0 forever)
    {
        const short8 z8 = {0, 0, 0, 0, 0, 0, 0, 0};
        for (int i = tid; i < 16 * 512 / 8; i += 256) {
            ((short8*)hsh)[i] = z8;
            ((short8*)hsl)[i] = z8;
        }
    }
    if (tid < 64) {
        const int gg = tid >> 4, cc = tid & 15;
        const float* bi_ = layer ? b_ih1 : b_ih0;
        const float* bh_ = layer ? b_hh1 : b_hh0;
        bbuf[gg][cc] = bi_[gg * 256 + j0 + cc] + bh_[gg * 256 + j0 + cc];
    }

    // ---- A-fragments: weight slice -> bf16 hi/lo, resident in VGPRs ----
    // Frag layout (16x16x32): lane l holds A[row=l&15][k=(l>>4)*8 + j], j=0..7.
    short8 Ahi[4][4], Alo[4][4];  // [gate(Mtile)][wave-local ktile]
    {
        const short8 z8 = {0, 0, 0, 0, 0, 0, 0, 0};
        #pragma unroll
        for (int gg = 0; gg < 4; ++gg) {
            const int row = gg * 256 + j0 + ar;
            #pragma unroll
            for (int kt = 0; kt < 4; ++kt) {
                const int k = (wave * 4 + kt) * 32 + kq * 8;  // concat-k floats
                const float* src = nullptr;
                if (layer) {
                    src = (k < 256) ? (w_ih1 + (size_t)row * 256 + k)
                                    : (w_hh1 + (size_t)row * 256 + (k - 256));
                } else {
                    if (k < 64)       src = w_ih0 + (size_t)row * 64 + k;
                    else if (k < 320) src = w_hh0 + (size_t)row * 256 + (k - 64);
                }
                short8 hi8 = z8, lo8 = z8;
                if (src) {
                    const float4 a = ((const float4*)src)[0];
                    const float4 b = ((const float4*)src)[1];
                    const float wv[8] = {a.x, a.y, a.z, a.w, b.x, b.y, b.z, b.w};
                    #pragma unroll
                    for (int i = 0; i < 8; ++i) {
                        const unsigned short h = f2bf(wv[i]);
                        hi8[i] = (short)h;
                        lo8[i] = (short)f2bf(wv[i] - bf2f(h));
                    }
                }
                Ahi[gg][kt] = hi8;
                Alo[gg][kt] = lo8;
            }
        }
    }

    // elementwise ownership: thread (eb=batch, ecc=col); c stays in a register
    const int eb = tid >> 4, ecc = tid & 15;
    float creg = 0.f;

    u32* hown  = layer ? h1p : h0p;
    u32* gflag = flags + (size_t)g * GBLK * 32;
    const int hoff = layer ? 256 : 64;   // k-offset of the h_prev region

    // X prefetch (layer 0): one float4/thread covers 16 batches x 64 floats
    const int pb = tid >> 4, pf = tid & 15;
    float4 xpf = make_float4(0.f, 0.f, 0.f, 0.f);
    if (!layer)
        xpf = ((const float4*)(X + (size_t)(b0 + pb) * NFEAT))[pf];

    __syncthreads();  // LDS zero + bias visible

    for (int s = 0; s <= SEQ; ++s) {
        const int  t      = layer ? (s - 1) : s;
        const bool active = layer ? (s >= 1) : (s < SEQ);

        if (active) {
            const int par = t & 1, pp = par ^ 1;
            const int b = tid >> 4, f0 = tid & 15;   // staging: batch, chunk
            const int swz = (b & 7) << 3;

            if (t > 0) {  // h_prev (own layer), parity pp, packed words
                const u64* hp = (const u64*)(hown + (size_t)pp * HB
                                             + (size_t)(b0 + b) * HID + f0 * 16);
                u64 v[8];
                #pragma unroll
                for (int i = 0; i < 8; ++i) v[i] = ald64(hp + i);
                short8 h0v, l0v, h1v, l1v;
                #pragma unroll
                for (int i = 0; i < 4; ++i) {
                    const u32 w0 = (u32)v[i], w1 = (u32)(v[i] >> 32);
                    h0v[2*i]   = (short)(w0 >> 16); l0v[2*i]   = (short)(w0 & 0xffff);
                    h0v[2*i+1] = (short)(w1 >> 16); l0v[2*i+1] = (short)(w1 & 0xffff);
                    const u32 w2 = (u32)v[i+4], w3 = (u32)(v[i+4] >> 32);
                    h1v[2*i]   = (short)(w2 >> 16); l1v[2*i]   = (short)(w2 & 0xffff);
                    h1v[2*i+1] = (short)(w3 >> 16); l1v[2*i+1] = (short)(w3 & 0xffff);
                }
                const int us = b * 512 + hoff + f0 * 16;
                *(short8*)&hsh[us ^ swz]       = h0v;
                *(short8*)&hsh[(us + 8) ^ swz] = h1v;
                *(short8*)&hsl[us ^ swz]       = l0v;
                *(short8*)&hsl[(us + 8) ^ swz] = l1v;
            }
            if (layer) {  // x = h0[t], parity par, packed words
                const u64* xp = (const u64*)(h0p + (size_t)par * HB
                                             + (size_t)(b0 + b) * HID + f0 * 16);
                u64 v[8];
                #pragma unroll
                for (int i = 0; i < 8; ++i) v[i] = ald64(xp + i);
                short8 h0v, l0v, h1v, l1v;
                #pragma unroll
                for (int i = 0; i < 4; ++i) {
                    const u32 w0 = (u32)v[i], w1 = (u32)(v[i] >> 32);
                    h0v[2*i]   = (short)(w0 >> 16); l0v[2*i]   = (short)(w0 & 0xffff);
                    h0v[2*i+1] = (short)(w1 >> 16); l0v[2*i+1] = (short)(w1 & 0xffff);
                    const u32 w2 = (u32)v[i+4], w3 = (u32)(v[i+4] >> 32);
                    h1v[2*i]   = (short)(w2 >> 16); l1v[2*i]   = (short)(w2 & 0xffff);
                    h1v[2*i+1] = (short)(w3 >> 16); l1v[2*i+1] = (short)(w3 & 0xffff);
                }
                const int us = b * 512 + f0 * 16;
                *(short8*)&hsh[us ^ swz]       = h0v;
                *(short8*)&hsh[(us + 8) ^ swz] = h1v;
                *(short8*)&hsl[us ^ swz]       = l0v;
                *(short8*)&hsl[(us + 8) ^ swz] = l1v;
            } else {      // x from prefetched X (convert fp32 -> hi/lo)
                const float xv[4] = {xpf.x, xpf.y, xpf.z, xpf.w};
                us4 xh, xl;
                #pragma unroll
                for (int i = 0; i < 4; ++i) {
                    const unsigned short hh = f2bf(xv[i]);
                    xh[i] = hh;
                    xl[i] = f2bf(xv[i] - bf2f(hh));
                }
                const int us = pb * 512 + pf * 4;
                const int sw = (pb & 7) << 3;
                *(us4*)&hsh[us ^ sw] = xh;
                *(us4*)&hsl[us ^ sw] = xl;
            }
        }
        __syncthreads();  // S1: staged planes visible

        // next X prefetch (layer 0); has a full step to land
        if (!layer && t + 1 < SEQ)
            xpf = ((const float4*)(X + (size_t)(t + 1) * BATCH * NFEAT
                                     + (size_t)(b0 + pb) * NFEAT))[pf];

        if (active) {
            f32x4 acc[4];
            #pragma unroll
            for (int gg = 0; gg < 4; ++gg)
                acc[gg] = (f32x4){0.f, 0.f, 0.f, 0.f};

            #pragma unroll
            for (int kt = 0; kt < 4; ++kt) {
                const int KT = wave * 4 + kt;
                const int us = ar * 512 + KT * 32 + kq * 8;
                const int uswz = us ^ ((ar & 7) << 3);
                const short8 bh = *(const short8*)&hsh[uswz];
                const short8 bl = *(const short8*)&hsl[uswz];
                #pragma unroll
                for (int gg = 0; gg < 4; ++gg)
                    acc[gg] = __builtin_amdgcn_mfma_f32_16x16x32_bf16(
                        Ahi[gg][kt], bh, acc[gg], 0, 0, 0);
                #pragma unroll
                for (int gg = 0; gg < 4; ++gg)
                    acc[gg] = __builtin_amdgcn_mfma_f32_16x16x32_bf16(
                        Alo[gg][kt], bh, acc[gg], 0, 0, 0);
                #pragma unroll
                for (int gg = 0; gg < 4; ++gg)
                    acc[gg] = __builtin_amdgcn_mfma_f32_16x16x32_bf16(
                        Ahi[gg][kt], bl, acc[gg], 0, 0, 0);
            }
            // partial C -> LDS; C layout: col(batch)=ar, row(colidx)=kq*4+i
            #pragma unroll
            for (int gg = 0; gg < 4; ++gg)
                *(f32x4*)&red[wave][gg][ar][kq * 4] = acc[gg];
        }
        __syncthreads();  // S2: partials visible

        if (active) {
            const int par = t & 1;
            float p[4];
            #pragma unroll
            for (int gg = 0; gg < 4; ++gg)
                p[gg] = bbuf[gg][ecc] + red[0][gg][eb][ecc] + red[1][gg][eb][ecc]
                                      + red[2][gg][eb][ecc] + red[3][gg][eb][ecc];
            const float ig  = 1.0f / (1.0f + __expf(-p[0]));
            const float fg  = 1.0f / (1.0f + __expf(-p[1]));
            const float gg_ = tanhf(p[2]);
            const float og  = 1.0f / (1.0f + __expf(-p[3]));
            creg = fg * creg + ig * gg_;
            const float hv = og * tanhf(creg);
            // pack hi|lo and publish via agent-scope store (IF coherent)
            const unsigned short hi = f2bf(hv);
            const unsigned short lo = f2bf(hv - bf2f(hi));
            ast32(&hown[(size_t)par * HB + (size_t)(b0 + eb) * HID + j0 + ecc],
                  ((u32)hi << 16) | (u32)lo);
        }

        // ---- group barrier (32 blocks), round rr = s+1 (round-6-verified) ----
        if (s < SEQ) {
            const u32 rr = (u32)(s + 1);
            __syncthreads();  // drains vmcnt: h stores acked at coherence point
            if (tid == 0)
                ast32(&gflag[rk * 32], rr);
            if (tid < GBLK) {
                int guard = 0;
                while (ald32(&gflag[tid * 32]) < rr && ++guard < (1 << 26))
                    __builtin_amdgcn_s_sleep(1);
            }
            __syncthreads();
        }
    }
}

// out[b] = dot(h1_last[b,:], fc_w) + fc_b ; h1 arrives as packed hi|lo words
__global__ __launch_bounds__(64) void fc_kernel(
    const u32* __restrict__ h1last_p,
    const float* __restrict__ fc_w,
    const float* __restrict__ fc_b,
    float* __restrict__ out)
{
    const int b    = blockIdx.x;
    const int lane = threadIdx.x;
    float sum = 0.0f;
    #pragma unroll
    for (int k = lane; k < HID; k += 64) {
        const u32 w = h1last_p[(size_t)b * HID + k];
        const float h = bf2f((unsigned short)(w >> 16))
                      + bf2f((unsigned short)(w & 0xffff));
        sum += h * fc_w[k];
    }
    #pragma unroll
    for (int off = 32; off > 0; off >>= 1)
        sum += __shfl_down(sum, off);
    if (lane == 0) out[b] = sum + fc_b[0];
}

extern "C" void kernel_launch(void* const* d_in, const int* in_sizes, int n_in,
                              void* d_out, int out_size, void* d_ws, size_t ws_size,
                              hipStream_t stream)
{
    const float* X     = (const float*)d_in[0];
    const float* w_ih0 = (const float*)d_in[1];
    const float* w_hh0 = (const float*)d_in[2];
    const float* b_ih0 = (const float*)d_in[3];
    const float* b_hh0 = (const float*)d_in[4];
    const float* w_ih1 = (const float*)d_in[5];
    const float* w_hh1 = (const float*)d_in[6];
    const float* b_ih1 = (const float*)d_in[7];
    const float* b_hh1 = (const float*)d_in[8];
    const float* fc_w  = (const float*)d_in[9];
    const float* fc_b  = (const float*)d_in[10];

    u32* h0p   = (u32*)d_ws;             // [2][HB] packed
    u32* h1p   = h0p + 2 * HB;           // [2][HB] packed
    u32* flags = h1p + 2 * HB;           // NGRP*GBLK slots, stride 32 u32

    // zero h buffers + flags every call (graph replays the memset, so stale
    // state can never leak across replays)
    const size_t zbytes = (size_t)(4 * HB + NGRP * GBLK * 32) * sizeof(u32);
    (void)hipMemsetAsync(d_ws, 0, zbytes, stream);

    lstm_persist<<<NGRP * GBLK, 256, 0, stream>>>(X,
        w_ih0, w_hh0, b_ih0, b_hh0,
        w_ih1, w_hh1, b_ih1, b_hh1,
        h0p, h1p, flags);

    // h1 for t=511 lives in parity buffer (511 & 1) = 1
    fc_kernel<<<BATCH, 64, 0, stream>>>(h1p + HB, fc_w, fc_b, (float*)d_out);
}

// Round 10
// 2096.118 us; speedup vs baseline: 2.3579x; 1.0091x over previous
//
#include <hip/hip_runtime.h>

#define SEQ   512
#define BATCH 128
#define NFEAT 64
#define HID   256
#define HB    (BATCH * HID)   // 32768
#define NGRP  8               // batch groups (16 batches each)
#define GBLK  32              // blocks per group: 2 layers x 16 col-tiles

// ---------------------------------------------------------------------------
// Persistent 2-layer LSTM, 256 blocks x 256 threads (1 block/CU).
// Group g (32 blocks = 2 layers x 16 col-tiles) owns batches [g*16,g*16+16).
// DEPENDENCY-SHAPED SYNC (this round): no lockstep barrier. Each block loops
// over its own t. Flag[rk] = v  <=>  block rk completed step v-1 (staged,
// computed, h[v-1] stored & drained). Preconditions polled at step t start:
//   L0: flag0[*] >= t   (peers' h0[t-1] stored -> staging safe)
//       flag1[*] >= t-1 (L1 staged x=h0[t-2] -> overwriting parity slot safe)
//   L1: flag1[*] >= t   (peers' h1[t-1] stored)
//       flag0[*] >= t+1 (h0[t] stored -> x staging safe)
// Cross-layer thresholds are one round stale in steady state -> instant;
// critical path = own 16-block domain. Own-layer condition also certifies
// write safety (peers finished step t-1 staging), so ONE poll phase + ONE
// flag post per step. Hot-spin polls (no s_sleep); skip own flag; guards
// 1<<18 so a protocol bug -> wrong answer, never a timeout.
// Memory primitives: round-6/9-verified agent-scope RELAXED atomics only.
// h crosses blocks as packed u32 [bf16_hi|bf16_lo] (round-7/9-verified).
// Matmul: round-6-verified MFMA bf16 hi/lo split, A-frags resident in VGPRs,
// XOR-swizzled LDS B-planes; partial C as float4 into red[4][4][16][20].
// c state stays in its owning thread's register.
// ---------------------------------------------------------------------------

typedef unsigned u32;
typedef unsigned long long u64;
typedef __attribute__((ext_vector_type(8))) short  short8;
typedef __attribute__((ext_vector_type(4))) float  f32x4;
typedef __attribute__((ext_vector_type(4))) unsigned short us4;

__device__ __forceinline__ unsigned short f2bf(float f) {  // RNE
    union { float f; unsigned u; } c; c.f = f;
    unsigned r = c.u + 0x7FFF + ((c.u >> 16) & 1);
    return (unsigned short)(r >> 16);
}
__device__ __forceinline__ float bf2f(unsigned short h) {
    union { float f; unsigned u; } c; c.u = ((unsigned)h) << 16;
    return c.f;
}

// agent-scope (IF coherence point) relaxed atomics -- the ONLY cross-block
// memory primitives in this kernel (round-6/9-verified codegen).
__device__ __forceinline__ u64 ald64(const u64* p) {
    return __hip_atomic_load(p, __ATOMIC_RELAXED, __HIP_MEMORY_SCOPE_AGENT);
}
__device__ __forceinline__ u32 ald32(const u32* p) {
    return __hip_atomic_load(p, __ATOMIC_RELAXED, __HIP_MEMORY_SCOPE_AGENT);
}
__device__ __forceinline__ void ast32(u32* p, u32 v) {
    __hip_atomic_store(p, v, __ATOMIC_RELAXED, __HIP_MEMORY_SCOPE_AGENT);
}

__global__ __launch_bounds__(256, 1) void lstm_persist(
    const float* __restrict__ X,      // [512][128][64]
    const float* __restrict__ w_ih0,  // [1024][64]
    const float* __restrict__ w_hh0,  // [1024][256]
    const float* __restrict__ b_ih0,
    const float* __restrict__ b_hh0,
    const float* __restrict__ w_ih1,  // [1024][256]
    const float* __restrict__ w_hh1,  // [1024][256]
    const float* __restrict__ b_ih1,
    const float* __restrict__ b_hh1,
    u32* __restrict__ h0p,            // [2][HB] packed hi|lo
    u32* __restrict__ h1p,            // [2][HB] packed hi|lo
    u32* __restrict__ flags)          // [NGRP][GBLK] stride 32 u32 (128 B)
{
    const int bid = blockIdx.x;
    const int tid = threadIdx.x;
    const int g     = bid >> 5;        // batch group 0..7
    const int rk    = bid & 31;        // rank in group
    const int layer = rk >> 4;         // 0 or 1
    const int ct    = rk & 15;         // col tile
    const int b0    = g * 16;          // 16 batches
    const int j0    = ct * 16;         // 16 h-cols

    const int wave = tid >> 6;
    const int l    = tid & 63;
    const int kq   = l >> 4;           // k-quarter within a k-tile
    const int ar   = l & 15;           // A row / B col (batch) within tile

    // bf16 planes of the [x;h] concat (k = 512; layer0 uses [0,320), rest 0)
    __shared__ __align__(16) unsigned short hsh[16 * 512];
    __shared__ __align__(16) unsigned short hsl[16 * 512];
    __shared__ float red[4][4][16][20];   // [wave][gate][batch(ar)][col], f4 st
    __shared__ float bbuf[4][16];         // bias sums [gate][col]

    // zero bf16 planes once (layer0's k >= 320 must stay 0 forever)
    {
        const short8 z8 = {0, 0, 0, 0, 0, 0, 0, 0};
        for (int i = tid; i < 16 * 512 / 8; i += 256) {
            ((short8*)hsh)[i] = z8;
            ((short8*)hsl)[i] = z8;
        }
    }
    if (tid < 64) {
        const int gg = tid >> 4, cc = tid & 15;
        const float* bi_ = layer ? b_ih1 : b_ih0;
        const float* bh_ = layer ? b_hh1 : b_hh0;
        bbuf[gg][cc] = bi_[gg * 256 + j0 + cc] + bh_[gg * 256 + j0 + cc];
    }

    // ---- A-fragments: weight slice -> bf16 hi/lo, resident in VGPRs ----
    // Frag layout (16x16x32): lane l holds A[row=l&15][k=(l>>4)*8 + j], j=0..7.
    short8 Ahi[4][4], Alo[4][4];  // [gate(Mtile)][wave-local ktile]
    {
        const short8 z8 = {0, 0, 0, 0, 0, 0, 0, 0};
        #pragma unroll
        for (int gg = 0; gg < 4; ++gg) {
            const int row = gg * 256 + j0 + ar;
            #pragma unroll
            for (int kt = 0; kt < 4; ++kt) {
                const int k = (wave * 4 + kt) * 32 + kq * 8;  // concat-k floats
                const float* src = nullptr;
                if (layer) {
                    src = (k < 256) ? (w_ih1 + (size_t)row * 256 + k)
                                    : (w_hh1 + (size_t)row * 256 + (k - 256));
                } else {
                    if (k < 64)       src = w_ih0 + (size_t)row * 64 + k;
                    else if (k < 320) src = w_hh0 + (size_t)row * 256 + (k - 64);
                }
                short8 hi8 = z8, lo8 = z8;
                if (src) {
                    const float4 a = ((const float4*)src)[0];
                    const float4 b = ((const float4*)src)[1];
                    const float wv[8] = {a.x, a.y, a.z, a.w, b.x, b.y, b.z, b.w};
                    #pragma unroll
                    for (int i = 0; i < 8; ++i) {
                        const unsigned short h = f2bf(wv[i]);
                        hi8[i] = (short)h;
                        lo8[i] = (short)f2bf(wv[i] - bf2f(h));
                    }
                }
                Ahi[gg][kt] = hi8;
                Alo[gg][kt] = lo8;
            }
        }
    }

    // elementwise ownership: thread (eb=batch, ecc=col); c stays in a register
    const int eb = tid >> 4, ecc = tid & 15;
    float creg = 0.f;

    u32* hown  = layer ? h1p : h0p;
    u32* gflag = flags + (size_t)g * GBLK * 32;
    const int hoff = layer ? 256 : 64;   // k-offset of the h_prev region

    // X prefetch (layer 0): one float4/thread covers 16 batches x 64 floats
    const int pb = tid >> 4, pf = tid & 15;
    float4 xpf = make_float4(0.f, 0.f, 0.f, 0.f);
    if (!layer)
        xpf = ((const float4*)(X + (size_t)(b0 + pb) * NFEAT))[pf];

    __syncthreads();  // LDS zero + bias visible

    for (int t = 0; t < SEQ; ++t) {
        // ---- WAIT: dependency-shaped poll (32 lanes, hot spin) ----
        {
            // lane < 16: own-layer flag[lane] >= t          (skip lane == ct)
            // lane in [16,32): other-layer flag[lane-16] >= (L1 ? t+1 : t-1)
            u32 thr;
            int idx;
            if (tid < 16) {
                idx = layer * 16 + tid;
                thr = (u32)t;
                if (tid == ct) thr = 0;           // own flag trivially true
            } else {
                idx = (1 - layer) * 16 + (tid - 16);
                thr = layer ? (u32)(t + 1) : (u32)(t > 0 ? t - 1 : 0);
            }
            if (tid < 32 && thr > 0) {
                int guard = 0;
                while (ald32(&gflag[idx * 32]) < thr && ++guard < (1 << 18)) {}
            }
            __syncthreads();
        }

        const int par = t & 1, pp = par ^ 1;
        const int b = tid >> 4, f0 = tid & 15;   // staging: batch, chunk
        const int swz = (b & 7) << 3;

        if (t > 0) {  // h_prev (own layer), parity pp, packed words
            const u64* hp = (const u64*)(hown + (size_t)pp * HB
                                         + (size_t)(b0 + b) * HID + f0 * 16);
            u64 v[8];
            #pragma unroll
            for (int i = 0; i < 8; ++i) v[i] = ald64(hp + i);
            short8 h0v, l0v, h1v, l1v;
            #pragma unroll
            for (int i = 0; i < 4; ++i) {
                const u32 w0 = (u32)v[i], w1 = (u32)(v[i] >> 32);
                h0v[2*i]   = (short)(w0 >> 16); l0v[2*i]   = (short)(w0 & 0xffff);
                h0v[2*i+1] = (short)(w1 >> 16); l0v[2*i+1] = (short)(w1 & 0xffff);
                const u32 w2 = (u32)v[i+4], w3 = (u32)(v[i+4] >> 32);
                h1v[2*i]   = (short)(w2 >> 16); l1v[2*i]   = (short)(w2 & 0xffff);
                h1v[2*i+1] = (short)(w3 >> 16); l1v[2*i+1] = (short)(w3 & 0xffff);
            }
            const int us = b * 512 + hoff + f0 * 16;
            *(short8*)&hsh[us ^ swz]       = h0v;
            *(short8*)&hsh[(us + 8) ^ swz] = h1v;
            *(short8*)&hsl[us ^ swz]       = l0v;
            *(short8*)&hsl[(us + 8) ^ swz] = l1v;
        }
        if (layer) {  // x = h0[t], parity par, packed words
            const u64* xp = (const u64*)(h0p + (size_t)par * HB
                                         + (size_t)(b0 + b) * HID + f0 * 16);
            u64 v[8];
            #pragma unroll
            for (int i = 0; i < 8; ++i) v[i] = ald64(xp + i);
            short8 h0v, l0v, h1v, l1v;
            #pragma unroll
            for (int i = 0; i < 4; ++i) {
                const u32 w0 = (u32)v[i], w1 = (u32)(v[i] >> 32);
                h0v[2*i]   = (short)(w0 >> 16); l0v[2*i]   = (short)(w0 & 0xffff);
                h0v[2*i+1] = (short)(w1 >> 16); l0v[2*i+1] = (short)(w1 & 0xffff);
                const u32 w2 = (u32)v[i+4], w3 = (u32)(v[i+4] >> 32);
                h1v[2*i]   = (short)(w2 >> 16); l1v[2*i]   = (short)(w2 & 0xffff);
                h1v[2*i+1] = (short)(w3 >> 16); l1v[2*i+1] = (short)(w3 & 0xffff);
            }
            const int us = b * 512 + f0 * 16;
            *(short8*)&hsh[us ^ swz]       = h0v;
            *(short8*)&hsh[(us + 8) ^ swz] = h1v;
            *(short8*)&hsl[us ^ swz]       = l0v;
            *(short8*)&hsl[(us + 8) ^ swz] = l1v;
        } else {      // x from prefetched X (convert fp32 -> hi/lo)
            const float xv[4] = {xpf.x, xpf.y, xpf.z, xpf.w};
            us4 xh, xl;
            #pragma unroll
            for (int i = 0; i < 4; ++i) {
                const unsigned short hh = f2bf(xv[i]);
                xh[i] = hh;
                xl[i] = f2bf(xv[i] - bf2f(hh));
            }
            const int us = pb * 512 + pf * 4;
            const int sw = (pb & 7) << 3;
            *(us4*)&hsh[us ^ sw] = xh;
            *(us4*)&hsl[us ^ sw] = xl;
        }
        __syncthreads();  // S1: staged planes visible

        // next X prefetch (layer 0); has a full step to land
        if (!layer && t + 1 < SEQ)
            xpf = ((const float4*)(X + (size_t)(t + 1) * BATCH * NFEAT
                                     + (size_t)(b0 + pb) * NFEAT))[pf];

        {
            f32x4 acc[4];
            #pragma unroll
            for (int gg = 0; gg < 4; ++gg)
                acc[gg] = (f32x4){0.f, 0.f, 0.f, 0.f};

            #pragma unroll
            for (int kt = 0; kt < 4; ++kt) {
                const int KT = wave * 4 + kt;
                const int us = ar * 512 + KT * 32 + kq * 8;
                const int uswz = us ^ ((ar & 7) << 3);
                const short8 bh = *(const short8*)&hsh[uswz];
                const short8 bl = *(const short8*)&hsl[uswz];
                #pragma unroll
                for (int gg = 0; gg < 4; ++gg)
                    acc[gg] = __builtin_amdgcn_mfma_f32_16x16x32_bf16(
                        Ahi[gg][kt], bh, acc[gg], 0, 0, 0);
                #pragma unroll
                for (int gg = 0; gg < 4; ++gg)
                    acc[gg] = __builtin_amdgcn_mfma_f32_16x16x32_bf16(
                        Alo[gg][kt], bh, acc[gg], 0, 0, 0);
                #pragma unroll
                for (int gg = 0; gg < 4; ++gg)
                    acc[gg] = __builtin_amdgcn_mfma_f32_16x16x32_bf16(
                        Ahi[gg][kt], bl, acc[gg], 0, 0, 0);
            }
            // partial C -> LDS; C layout: col(batch)=ar, row(colidx)=kq*4+i
            #pragma unroll
            for (int gg = 0; gg < 4; ++gg)
                *(f32x4*)&red[wave][gg][ar][kq * 4] = acc[gg];
        }
        __syncthreads();  // S2: partials visible

        {
            float p[4];
            #pragma unroll
            for (int gg = 0; gg < 4; ++gg)
                p[gg] = bbuf[gg][ecc] + red[0][gg][eb][ecc] + red[1][gg][eb][ecc]
                                      + red[2][gg][eb][ecc] + red[3][gg][eb][ecc];
            const float ig  = 1.0f / (1.0f + __expf(-p[0]));
            const float fg  = 1.0f / (1.0f + __expf(-p[1]));
            const float gg_ = tanhf(p[2]);
            const float og  = 1.0f / (1.0f + __expf(-p[3]));
            creg = fg * creg + ig * gg_;
            const float hv = og * tanhf(creg);
            // pack hi|lo and publish via agent-scope store (IF coherent)
            const unsigned short hi = f2bf(hv);
            const unsigned short lo = f2bf(hv - bf2f(hi));
            ast32(&hown[(size_t)par * HB + (size_t)(b0 + eb) * HID + j0 + ecc],
                  ((u32)hi << 16) | (u32)lo);
        }

        // ---- completion post: drain h stores, then flag = t+1 ----
        __syncthreads();  // drains vmcnt: all h stores acked at coherence point
        if (tid == 0)
            ast32(&gflag[rk * 32], (u32)(t + 1));
        // next iteration's WAIT syncthreads separates LDS reuse (red/hs*)
    }
}

// out[b] = dot(h1_last[b,:], fc_w) + fc_b ; h1 arrives as packed hi|lo words
__global__ __launch_bounds__(64) void fc_kernel(
    const u32* __restrict__ h1last_p,
    const float* __restrict__ fc_w,
    const float* __restrict__ fc_b,
    float* __restrict__ out)
{
    const int b    = blockIdx.x;
    const int lane = threadIdx.x;
    float sum = 0.0f;
    #pragma unroll
    for (int k = lane; k < HID; k += 64) {
        const u32 w = h1last_p[(size_t)b * HID + k];
        const float h = bf2f((unsigned short)(w >> 16))
                      + bf2f((unsigned short)(w & 0xffff));
        sum += h * fc_w[k];
    }
    #pragma unroll
    for (int off = 32; off > 0; off >>= 1)
        sum += __shfl_down(sum, off);
    if (lane == 0) out[b] = sum + fc_b[0];
}

extern "C" void kernel_launch(void* const* d_in, const int* in_sizes, int n_in,
                              void* d_out, int out_size, void* d_ws, size_t ws_size,
                              hipStream_t stream)
{
    const float* X     = (const float*)d_in[0];
    const float* w_ih0 = (const float*)d_in[1];
    const float* w_hh0 = (const float*)d_in[2];
    const float* b_ih0 = (const float*)d_in[3];
    const float* b_hh0 = (const float*)d_in[4];
    const float* w_ih1 = (const float*)d_in[5];
    const float* w_hh1 = (const float*)d_in[6];
    const float* b_ih1 = (const float*)d_in[7];
    const float* b_hh1 = (const float*)d_in[8];
    const float* fc_w  = (const float*)d_in[9];
    const float* fc_b  = (const float*)d_in[10];

    u32* h0p   = (u32*)d_ws;             // [2][HB] packed
    u32* h1p   = h0p + 2 * HB;           // [2][HB] packed
    u32* flags = h1p + 2 * HB;           // NGRP*GBLK slots, stride 32 u32

    // zero h buffers + flags every call (graph replays the memset, so stale
    // state can never leak across replays)
    const size_t zbytes = (size_t)(4 * HB + NGRP * GBLK * 32) * sizeof(u32);
    (void)hipMemsetAsync(d_ws, 0, zbytes, stream);

    lstm_persist<<<NGRP * GBLK, 256, 0, stream>>>(X,
        w_ih0, w_hh0, b_ih0, b_hh0,
        w_ih1, w_hh1, b_ih1, b_hh1,
        h0p, h1p, flags);

    // h1 for t=511 lives in parity buffer (511 & 1) = 1
    fc_kernel<<<BATCH, 64, 0, stream>>>(h1p + HB, fc_w, fc_b, (float*)d_out);
}